// Round 2
// baseline (160.884 us; speedup 1.0000x reference)
//
#include <hip/hip_runtime.h>
#include <hip/hip_cooperative_groups.h>

namespace cg = cooperative_groups;

#define NPTS 8192
#define BLOCK 1024               // 16 waves, 1 block/CU -> 4 waves/SIMD
#define IB 32                    // i-rows per main block
#define NBLK (NPTS / IB)         // 256 blocks = 1 per CU
#define NTILES (NPTS / 16)       // 512 j-tiles
#define NW 16                    // waves per block
#define TPW (NTILES / NW)        // 32 tiles per wave
#define PF 3                     // prefetch distance

typedef __attribute__((ext_vector_type(8))) short bf16x8;
typedef __attribute__((ext_vector_type(4))) float f32x4;
typedef unsigned short u16;
typedef unsigned int u32;

// arg(base2) = C1*(ni+nj) + K2*dot6 ; closeness^2 = exp2(arg)
#define C1f (-144.26950408889634f)   // -100*log2(e)
#define C2f (-28.853900817779268f)   // out = s*exp2(C2*pen)
#define SQK2f (16.98643596886418f)   // sqrt(200*log2(e))
#define SKIP_TH (-50.0f)             // exp2(-50)*8192 ~ 1e-11 penalty err

static __device__ __forceinline__ u16 f2b(float f) {
    union { float f; u32 u; } v; v.f = f;
    u32 u = v.u;
    return (u16)((u + 0x7FFFu + ((u >> 16) & 1u)) >> 16);   // RN-even
}
static __device__ __forceinline__ float b2f(u16 h) {
    union { u32 u; float f; } v; v.u = ((u32)h) << 16;
    return v.f;
}

struct Split { u16 uh[6], ul[6], ch, cm, cl; };

static __device__ __forceinline__ Split mksplit(
    const float* __restrict__ src, const float* __restrict__ tgt, int p)
{
    float x[6];
    x[0] = src[p * 3 + 0]; x[1] = src[p * 3 + 1]; x[2] = src[p * 3 + 2];
    x[3] = tgt[p * 3 + 0]; x[4] = tgt[p * 3 + 1]; x[5] = tgt[p * 3 + 2];
    float n = 0.0f;
    #pragma unroll
    for (int d = 0; d < 6; d++) n += x[d] * x[d];
    float c = C1f * n;
    Split s;
    #pragma unroll
    for (int d = 0; d < 6; d++) {
        float u = SQK2f * x[d];
        u16   h = f2b(u);
        s.uh[d] = h;
        s.ul[d] = f2b(u - b2f(h));
    }
    s.ch = f2b(c);
    float r1 = c - b2f(s.ch);
    s.cm = f2b(r1);
    s.cl = f2b(r1 - b2f(s.cm));
    return s;
}

#define PK(lo, hi) (((u32)(u16)(lo)) | (((u32)(u16)(hi)) << 16))
static __device__ __forceinline__ void emit_a(const Split& s, uint4* da) {
    const u32 one = 0x3F80u;
    da[0] = make_uint4(PK(s.uh[0],s.uh[1]), PK(s.uh[2],s.uh[3]), PK(s.uh[4],s.uh[5]), PK(s.uh[0],s.uh[1]));
    da[1] = make_uint4(PK(s.uh[2],s.uh[3]), PK(s.uh[4],s.uh[5]), PK(s.ul[0],s.ul[1]), PK(s.ul[2],s.ul[3]));
    da[2] = make_uint4(PK(s.ul[4],s.ul[5]), PK(s.ul[0],s.ul[1]), PK(s.ul[2],s.ul[3]), PK(s.ul[4],s.ul[5]));
    da[3] = make_uint4(PK(s.ch, s.cm),      PK(s.cl, one),       PK(one, one),        0u);
}
static __device__ __forceinline__ void emit_b(const Split& s, uint4* db) {
    const u32 one = 0x3F80u;
    db[0] = make_uint4(PK(s.uh[0],s.uh[1]), PK(s.uh[2],s.uh[3]), PK(s.uh[4],s.uh[5]), PK(s.ul[0],s.ul[1]));
    db[1] = make_uint4(PK(s.ul[2],s.ul[3]), PK(s.ul[4],s.ul[5]), PK(s.uh[0],s.uh[1]), PK(s.uh[2],s.uh[3]));
    db[2] = make_uint4(PK(s.uh[4],s.uh[5]), PK(s.ul[0],s.ul[1]), PK(s.ul[2],s.ul[3]), PK(s.ul[4],s.ul[5]));
    db[3] = make_uint4(PK(one, one),        PK(one, s.ch),       PK(s.cm, s.cl),      0u);
}
#undef PK

// Fused: per-block prep of its own 32 points (B-tiles -> global Bg, A-frags -> LDS),
// grid-wide cooperative sync, then the MFMA soft-NMS main loop.
// A-frag: A[m][k], m=lane&15, k=(lane>>4)*8+idx. C/D: col=lane&15, row=(lane>>4)*4+r.
// Per-block stagger spreads 4096 waves across the 512 j-tiles (anti L2-hotspot).
__global__ __launch_bounds__(BLOCK, 4) void fused_kernel(
    const float* __restrict__ src, const float* __restrict__ tgt,
    const float* __restrict__ scores,
    u16* __restrict__ Bg, float* __restrict__ out)
{
    __shared__ float red[NW][IB];
    __shared__ uint4 lA[2][64];          // 2 A-tiles, 1 KB each

    const int t    = threadIdx.x;
    const int lane = t & 63;
    const int wid  = t >> 6;
    const int half = lane & 15;
    const int quad = lane >> 4;
    const int bx   = blockIdx.x;
    const int i0   = bx * IB;

    // ---- phase 1: prep own 32 points ----
    if (t < IB) {
        const int p = i0 + t;
        Split s = mksplit(src, tgt, p);
        uint4 a[4], b[4];
        emit_a(s, a);
        emit_b(s, b);
        uint4* Bg4 = (uint4*)Bg;
        const int base = (p >> 4) * 64 + (p & 15);
        const int m = t & 15, ts = t >> 4;
        #pragma unroll
        for (int q = 0; q < 4; q++) {
            Bg4[base + q * 16] = b[q];
            lA[ts][m + q * 16]  = a[q];
        }
    }

    // i-row scores (input array, safe to read pre-sync)
    float si[2][4], acc[2][4];
    #pragma unroll
    for (int s = 0; s < 2; s++)
        #pragma unroll
        for (int r = 0; r < 4; r++) {
            si[s][r]  = scores[i0 + s * 16 + quad * 4 + r];
            acc[s][r] = 0.0f;
        }

    __threadfence();                      // release Bg writes device-wide
    cg::this_grid().sync();               // all B-tiles visible; LDS lA ready

    bf16x8 afrag[2];
    #pragma unroll
    for (int s = 0; s < 2; s++)
        afrag[s] = *(const bf16x8*)&lA[s][lane];

    const int wgrp  = (wid + bx) & (NW - 1);     // staggered wave-group
    const int phase = (bx >> 4) & (TPW - 1);     // staggered start phase

    const f32x4 zero = {0.0f, 0.0f, 0.0f, 0.0f};

    // prefetch pipeline, depth PF
    bf16x8 bpf[PF];
    float  spf[PF];
    #pragma unroll
    for (int q = 0; q < PF; q++) {
        const int tq = wgrp * TPW + ((q + phase) & (TPW - 1));
        bpf[q] = *(const bf16x8*)(Bg + (size_t)tq * 512 + lane * 8);
        spf[q] = scores[tq * 16 + half];
    }

    #pragma unroll 4
    for (int u = 0; u < TPW; u++) {
        bf16x8 bfrag = bpf[0];
        float  sj    = spf[0];
        #pragma unroll
        for (int q = 0; q < PF - 1; q++) { bpf[q] = bpf[q + 1]; spf[q] = spf[q + 1]; }
        // issue next prefetch (wraps at end; harmless)
        const int tn = wgrp * TPW + ((u + PF + phase) & (TPW - 1));
        bpf[PF - 1] = *(const bf16x8*)(Bg + (size_t)tn * 512 + lane * 8);
        spf[PF - 1] = scores[tn * 16 + half];

        f32x4 d0 = __builtin_amdgcn_mfma_f32_16x16x32_bf16(afrag[0], bfrag, zero, 0, 0, 0);
        f32x4 d1 = __builtin_amdgcn_mfma_f32_16x16x32_bf16(afrag[1], bfrag, zero, 0, 0, 0);

        float m0 = fmaxf(fmaxf(d0[0], d0[1]), fmaxf(d0[2], d0[3]));
        if (__any(m0 > SKIP_TH)) {
            #pragma unroll
            for (int r = 0; r < 4; r++) {
                float e = __builtin_amdgcn_exp2f(d0[r]);
                acc[0][r] += (sj > si[0][r]) ? e : 0.0f;
            }
        }
        float m1 = fmaxf(fmaxf(d1[0], d1[1]), fmaxf(d1[2], d1[3]));
        if (__any(m1 > SKIP_TH)) {
            #pragma unroll
            for (int r = 0; r < 4; r++) {
                float e = __builtin_amdgcn_exp2f(d1[r]);
                acc[1][r] += (sj > si[1][r]) ? e : 0.0f;
            }
        }
    }

    // reduce over 16 j-columns (half bits), then across 16 waves
    #pragma unroll
    for (int s = 0; s < 2; s++)
        #pragma unroll
        for (int r = 0; r < 4; r++) {
            float v = acc[s][r];
            v += __shfl_xor(v, 1);
            v += __shfl_xor(v, 2);
            v += __shfl_xor(v, 4);
            v += __shfl_xor(v, 8);
            if (half == 0) red[wid][s * 16 + quad * 4 + r] = v;
        }
    __syncthreads();
    if (t < IB) {
        float p = 0.0f;
        #pragma unroll
        for (int w = 0; w < NW; w++) p += red[w][t];
        out[i0 + t] = scores[i0 + t] * __builtin_amdgcn_exp2f(C2f * p);
    }
}

extern "C" void kernel_launch(void* const* d_in, const int* in_sizes, int n_in,
                              void* d_out, int out_size, void* d_ws, size_t ws_size,
                              hipStream_t stream) {
    const float* src    = (const float*)d_in[0];
    const float* tgt    = (const float*)d_in[1];
    const float* scores = (const float*)d_in[2];
    float* out = (float*)d_out;

    u16* Bg = (u16*)d_ws;                        // 512 KB, fragment-ordered

    void* args[] = {(void*)&src, (void*)&tgt, (void*)&scores, (void*)&Bg, (void*)&out};
    hipLaunchCooperativeKernel((void*)fused_kernel, dim3(NBLK), dim3(BLOCK),
                               args, 0, stream);
}

// Round 3
// 71.114 us; speedup vs baseline: 2.2623x; 2.2623x over previous
//
#include <hip/hip_runtime.h>

#define NPTS 8192
#define BLOCK 1024               // 16 waves, 1 block/CU -> 4 waves/SIMD
#define IB 32                    // i-rows per main block
#define NBLK (NPTS / IB)         // 256 blocks = 1 per CU
#define NW 16                    // waves per block
#define CPTS 1024                // j-points per chunk (1 per thread)
#define CTIL (CPTS / 16)         // 64 j-tiles per chunk
#define NCH (NPTS / CPTS)        // 8 chunks
#define TPWC (CTIL / NW)         // 4 tiles per wave per chunk

typedef __attribute__((ext_vector_type(8))) short bf16x8;
typedef __attribute__((ext_vector_type(4))) float f32x4;
typedef unsigned short u16;
typedef unsigned int u32;

// arg(base2) = C1*(ni+nj) + K2*dot6 ; closeness^2 = exp2(arg)
#define C1f (-144.26950408889634f)   // -100*log2(e)
#define C2f (-28.853900817779268f)   // out = s*exp2(C2*pen)
#define SQK2f (16.98643596886418f)   // sqrt(200*log2(e))
#define SKIP_TH (-50.0f)             // exp2(-50)*8192 ~ 1e-11 penalty err

static __device__ __forceinline__ u16 f2b(float f) {
    union { float f; u32 u; } v; v.f = f;
    u32 u = v.u;
    return (u16)((u + 0x7FFFu + ((u >> 16) & 1u)) >> 16);   // RN-even
}
static __device__ __forceinline__ float b2f(u16 h) {
    union { u32 u; float f; } v; v.u = ((u32)h) << 16;
    return v.f;
}

struct Split { u16 uh[6], ul[6], ch, cm, cl; };

static __device__ __forceinline__ Split mksplit6(const float x[6]) {
    float n = 0.0f;
    #pragma unroll
    for (int d = 0; d < 6; d++) n += x[d] * x[d];
    float c = C1f * n;
    Split s;
    #pragma unroll
    for (int d = 0; d < 6; d++) {
        float u = SQK2f * x[d];
        u16   h = f2b(u);
        s.uh[d] = h;
        s.ul[d] = f2b(u - b2f(h));
    }
    s.ch = f2b(c);
    float r1 = c - b2f(s.ch);
    s.cm = f2b(r1);
    s.cl = f2b(r1 - b2f(s.cm));
    return s;
}

#define PK(lo, hi) (((u32)(u16)(lo)) | (((u32)(u16)(hi)) << 16))
static __device__ __forceinline__ void emit_a(const Split& s, uint4* da) {
    const u32 one = 0x3F80u;
    da[0] = make_uint4(PK(s.uh[0],s.uh[1]), PK(s.uh[2],s.uh[3]), PK(s.uh[4],s.uh[5]), PK(s.uh[0],s.uh[1]));
    da[1] = make_uint4(PK(s.uh[2],s.uh[3]), PK(s.uh[4],s.uh[5]), PK(s.ul[0],s.ul[1]), PK(s.ul[2],s.ul[3]));
    da[2] = make_uint4(PK(s.ul[4],s.ul[5]), PK(s.ul[0],s.ul[1]), PK(s.ul[2],s.ul[3]), PK(s.ul[4],s.ul[5]));
    da[3] = make_uint4(PK(s.ch, s.cm),      PK(s.cl, one),       PK(one, one),        0u);
}
static __device__ __forceinline__ void emit_b(const Split& s, uint4* db) {
    const u32 one = 0x3F80u;
    db[0] = make_uint4(PK(s.uh[0],s.uh[1]), PK(s.uh[2],s.uh[3]), PK(s.uh[4],s.uh[5]), PK(s.ul[0],s.ul[1]));
    db[1] = make_uint4(PK(s.ul[2],s.ul[3]), PK(s.ul[4],s.ul[5]), PK(s.uh[0],s.uh[1]), PK(s.uh[2],s.uh[3]));
    db[2] = make_uint4(PK(s.uh[4],s.uh[5]), PK(s.ul[0],s.ul[1]), PK(s.ul[2],s.ul[3]), PK(s.ul[4],s.ul[5]));
    db[3] = make_uint4(PK(one, one),        PK(one, s.ch),       PK(s.cm, s.cl),      0u);
}
#undef PK

// Single launch, no grid sync (R2 post-mortem: coop sync across 8 XCDs = 86us
// dispatch + non-capturable launch). Each block recomputes ALL points' B-frags
// itself (~60 VALU/point, inputs L2/L3-resident and shared by all 256 blocks),
// staged per 64-tile chunk through double-buffered LDS (128 KB of 160 KB).
// Chunk c+1 global loads issue before chunk c's MFMAs (latency hidden);
// one __syncthreads per chunk.
// A-frag: A[m][k], m=lane&15, k=(lane>>4)*8+idx. C/D: col=lane&15, row=(lane>>4)*4+r.
__global__ __launch_bounds__(BLOCK, 4) void fused_kernel(
    const float* __restrict__ src, const float* __restrict__ tgt,
    const float* __restrict__ scores, float* __restrict__ out)
{
    __shared__ uint4 lB[2][CTIL][64];    // 2 x 64 KB: B-frag image, tile tt at tt*1024B
    __shared__ float lS[2][CPTS];        // 2 x 4 KB: j-scores
    __shared__ uint4 lA[2][64];          // 2 KB: this block's 2 A-tiles
    __shared__ float red[NW][IB];        // 2 KB

    const int t    = threadIdx.x;
    const int lane = t & 63;
    const int wid  = t >> 6;
    const int half = lane & 15;
    const int quad = lane >> 4;
    const int bx   = blockIdx.x;
    const int i0   = bx * IB;

    // ---- preload: chunk 0 B-frags (1 point/thread) + own A-frags ----
    {
        float x[6];
        x[0] = src[t * 3 + 0]; x[1] = src[t * 3 + 1]; x[2] = src[t * 3 + 2];
        x[3] = tgt[t * 3 + 0]; x[4] = tgt[t * 3 + 1]; x[5] = tgt[t * 3 + 2];
        float psc = scores[t];
        Split s = mksplit6(x);
        uint4 b[4];
        emit_b(s, b);
        #pragma unroll
        for (int q = 0; q < 4; q++) lB[0][t >> 4][(t & 15) + q * 16] = b[q];
        lS[0][t] = psc;
    }
    if (t < IB) {
        float x[6];
        const int p = i0 + t;
        x[0] = src[p * 3 + 0]; x[1] = src[p * 3 + 1]; x[2] = src[p * 3 + 2];
        x[3] = tgt[p * 3 + 0]; x[4] = tgt[p * 3 + 1]; x[5] = tgt[p * 3 + 2];
        Split s = mksplit6(x);
        uint4 a[4];
        emit_a(s, a);
        #pragma unroll
        for (int q = 0; q < 4; q++) lA[t >> 4][(t & 15) + q * 16] = a[q];
    }

    // i-row scores + accumulators
    float si[2][4], acc[2][4];
    #pragma unroll
    for (int s = 0; s < 2; s++)
        #pragma unroll
        for (int r = 0; r < 4; r++) {
            si[s][r]  = scores[i0 + s * 16 + quad * 4 + r];
            acc[s][r] = 0.0f;
        }

    __syncthreads();

    bf16x8 afrag[2];
    #pragma unroll
    for (int s = 0; s < 2; s++)
        afrag[s] = *(const bf16x8*)&lA[s][lane];

    const f32x4 zero = {0.0f, 0.0f, 0.0f, 0.0f};

    for (int c = 0; c < NCH; c++) {
        // issue next chunk's input loads early (hide L2 latency under MFMAs)
        float x[6], psc = 0.0f;
        const bool hasNext = (c < NCH - 1);
        if (hasNext) {
            const int p = (c + 1) * CPTS + t;
            x[0] = src[p * 3 + 0]; x[1] = src[p * 3 + 1]; x[2] = src[p * 3 + 2];
            x[3] = tgt[p * 3 + 0]; x[4] = tgt[p * 3 + 1]; x[5] = tgt[p * 3 + 2];
            psc = scores[p];
        }

        // consume chunk c: 4 tiles per wave, all from LDS
        const u16* lBu = (const u16*)&lB[c & 1][0][0];
        const float* lSc = &lS[c & 1][0];
        #pragma unroll
        for (int k = 0; k < TPWC; k++) {
            const int tt = wid * TPWC + k;
            bf16x8 bfrag = *(const bf16x8*)(lBu + tt * 512 + lane * 8);
            float   sj   = lSc[tt * 16 + half];

            f32x4 d0 = __builtin_amdgcn_mfma_f32_16x16x32_bf16(afrag[0], bfrag, zero, 0, 0, 0);
            f32x4 d1 = __builtin_amdgcn_mfma_f32_16x16x32_bf16(afrag[1], bfrag, zero, 0, 0, 0);

            float m0 = fmaxf(fmaxf(d0[0], d0[1]), fmaxf(d0[2], d0[3]));
            if (__any(m0 > SKIP_TH)) {
                #pragma unroll
                for (int r = 0; r < 4; r++) {
                    float e = __builtin_amdgcn_exp2f(d0[r]);
                    acc[0][r] += (sj > si[0][r]) ? e : 0.0f;
                }
            }
            float m1 = fmaxf(fmaxf(d1[0], d1[1]), fmaxf(d1[2], d1[3]));
            if (__any(m1 > SKIP_TH)) {
                #pragma unroll
                for (int r = 0; r < 4; r++) {
                    float e = __builtin_amdgcn_exp2f(d1[r]);
                    acc[1][r] += (sj > si[1][r]) ? e : 0.0f;
                }
            }
        }

        // write next chunk's B-frags into the other buffer
        if (hasNext) {
            Split s = mksplit6(x);
            uint4 b[4];
            emit_b(s, b);
            #pragma unroll
            for (int q = 0; q < 4; q++) lB[(c + 1) & 1][t >> 4][(t & 15) + q * 16] = b[q];
            lS[(c + 1) & 1][t] = psc;
        }
        __syncthreads();
    }

    // reduce over 16 j-columns (half bits), then across 16 waves
    #pragma unroll
    for (int s = 0; s < 2; s++)
        #pragma unroll
        for (int r = 0; r < 4; r++) {
            float v = acc[s][r];
            v += __shfl_xor(v, 1);
            v += __shfl_xor(v, 2);
            v += __shfl_xor(v, 4);
            v += __shfl_xor(v, 8);
            if (half == 0) red[wid][s * 16 + quad * 4 + r] = v;
        }
    __syncthreads();
    if (t < IB) {
        float p = 0.0f;
        #pragma unroll
        for (int w = 0; w < NW; w++) p += red[w][t];
        out[i0 + t] = scores[i0 + t] * __builtin_amdgcn_exp2f(C2f * p);
    }
}

extern "C" void kernel_launch(void* const* d_in, const int* in_sizes, int n_in,
                              void* d_out, int out_size, void* d_ws, size_t ws_size,
                              hipStream_t stream) {
    const float* src    = (const float*)d_in[0];
    const float* tgt    = (const float*)d_in[1];
    const float* scores = (const float*)d_in[2];
    float* out = (float*)d_out;

    fused_kernel<<<NBLK, BLOCK, 0, stream>>>(src, tgt, scores, out);
}

// Round 5
// 67.161 us; speedup vs baseline: 2.3955x; 1.0589x over previous
//
#include <hip/hip_runtime.h>

#define NPTS 8192
#define BLOCK 1024               // 16 waves, 1 block/CU -> 4 waves/SIMD
#define IB 32                    // i-rows per main block
#define NBLK (NPTS / IB)         // 256 blocks
#define NTILES (NPTS / 16)       // 512 j-tiles
#define NW 16                    // waves per block
#define TPW (NTILES / NW)        // 32 tiles per wave
#define PF 2                     // prefetch distance (R0-proven; R1 showed PF3 neutral)

typedef __attribute__((ext_vector_type(8))) short bf16x8;
typedef __attribute__((ext_vector_type(4))) float f32x4;
typedef unsigned short u16;
typedef unsigned int u32;

// arg(base2) = C1*(ni+nj) + K2*dot6 ; closeness^2 = exp2(arg)
#define C1f (-144.26950408889634f)   // -100*log2(e)
#define C2f (-28.853900817779268f)   // out = s*exp2(C2*pen)
#define SQK2f (16.98643596886418f)   // sqrt(200*log2(e))
#define SKIP_TH (-50.0f)             // exp2(-50)*8192 ~ 1e-11 penalty err

static __device__ __forceinline__ u16 f2b(float f) {
    union { float f; u32 u; } v; v.f = f;
    u32 u = v.u;
    return (u16)((u + 0x7FFFu + ((u >> 16) & 1u)) >> 16);   // RN-even
}
static __device__ __forceinline__ float b2f(u16 h) {
    union { u32 u; float f; } v; v.u = ((u32)h) << 16;
    return v.f;
}

struct Split { u16 uh[6], ul[6], ch, cm, cl; };

static __device__ __forceinline__ Split mksplit(
    const float* __restrict__ src, const float* __restrict__ tgt, int p)
{
    float x[6];
    x[0] = src[p * 3 + 0]; x[1] = src[p * 3 + 1]; x[2] = src[p * 3 + 2];
    x[3] = tgt[p * 3 + 0]; x[4] = tgt[p * 3 + 1]; x[5] = tgt[p * 3 + 2];
    float n = 0.0f;
    #pragma unroll
    for (int d = 0; d < 6; d++) n += x[d] * x[d];
    float c = C1f * n;
    Split s;
    #pragma unroll
    for (int d = 0; d < 6; d++) {
        float u = SQK2f * x[d];
        u16   h = f2b(u);
        s.uh[d] = h;
        s.ul[d] = f2b(u - b2f(h));
    }
    s.ch = f2b(c);
    float r1 = c - b2f(s.ch);
    s.cm = f2b(r1);
    s.cl = f2b(r1 - b2f(s.cm));
    return s;
}

#define PK(lo, hi) (((u32)(u16)(lo)) | (((u32)(u16)(hi)) << 16))
static __device__ __forceinline__ void emit_a(const Split& s, uint4* da) {
    const u32 one = 0x3F80u;
    da[0] = make_uint4(PK(s.uh[0],s.uh[1]), PK(s.uh[2],s.uh[3]), PK(s.uh[4],s.uh[5]), PK(s.uh[0],s.uh[1]));
    da[1] = make_uint4(PK(s.uh[2],s.uh[3]), PK(s.uh[4],s.uh[5]), PK(s.ul[0],s.ul[1]), PK(s.ul[2],s.ul[3]));
    da[2] = make_uint4(PK(s.ul[4],s.ul[5]), PK(s.ul[0],s.ul[1]), PK(s.ul[2],s.ul[3]), PK(s.ul[4],s.ul[5]));
    da[3] = make_uint4(PK(s.ch, s.cm),      PK(s.cl, one),       PK(one, one),        0u);
}
static __device__ __forceinline__ void emit_b(const Split& s, uint4* db) {
    const u32 one = 0x3F80u;
    db[0] = make_uint4(PK(s.uh[0],s.uh[1]), PK(s.uh[2],s.uh[3]), PK(s.uh[4],s.uh[5]), PK(s.ul[0],s.ul[1]));
    db[1] = make_uint4(PK(s.ul[2],s.ul[3]), PK(s.ul[4],s.ul[5]), PK(s.uh[0],s.uh[1]), PK(s.uh[2],s.uh[3]));
    db[2] = make_uint4(PK(s.uh[4],s.uh[5]), PK(s.ul[0],s.ul[1]), PK(s.ul[2],s.ul[3]), PK(s.ul[4],s.ul[5]));
    db[3] = make_uint4(PK(one, one),        PK(one, s.ch),       PK(s.cm, s.cl),      0u);
}
#undef PK

// Fragment-order tables: tile tt (16 points) occupies 1024 B; lane l's 16 B at
// tt*1024 + l*16 holds column[k = (l>>4)*8 .. +7][pt = tt*16 + (l&15)].
// 64 blocks x 128 thr (was 16x512 -> only 6% of CUs active).
__global__ __launch_bounds__(128) void prep_kernel(
    const float* __restrict__ src, const float* __restrict__ tgt,
    u16* __restrict__ Ag, u16* __restrict__ Bg)
{
    const int p = blockIdx.x * 128 + threadIdx.x;
    Split s = mksplit(src, tgt, p);
    uint4 a[4], b[4];
    emit_a(s, a);
    emit_b(s, b);
    uint4* Ag4 = (uint4*)Ag;
    uint4* Bg4 = (uint4*)Bg;
    const int base = (p >> 4) * 64 + (p & 15);
    #pragma unroll
    for (int q = 0; q < 4; q++) {
        Ag4[base + q * 16] = a[q];
        Bg4[base + q * 16] = b[q];
    }
}

// A-frag: A[m][k], m=lane&15, k=(lane>>4)*8+idx. C/D: col=lane&15, row=(lane>>4)*4+r.
// 16 waves/block (1 block/CU -> 4 waves/SIMD). Per-block stagger spreads the
// 4096 waves across the 512 tiles (anti L2-hotspot, R9 win).
// R4: score load moved inside the rare (2.7%) epilogue branch; combined __any
// gate; max3-fused reduction; readfirstlane-scalarized B addressing.
__global__ __launch_bounds__(BLOCK, 4) void main_kernel(
    const u16* __restrict__ Ag, const u16* __restrict__ Bg,
    const float* __restrict__ scores, float* __restrict__ out)
{
    __shared__ float red[NW][IB];

    const int t    = threadIdx.x;
    const int lane = t & 63;
    const int wid  = t >> 6;
    const int half = lane & 15;
    const int quad = lane >> 4;
    const int bx   = blockIdx.x;
    const int i0   = bx * IB;

    const int wgrp  = (wid + bx) & (NW - 1);     // staggered wave-group
    const int phase = (bx >> 4) & (TPW - 1);     // staggered start phase (SGPR)
    const int tb    = __builtin_amdgcn_readfirstlane(wgrp * TPW);  // scalar tile base

    bf16x8 afrag[2];
    float si[2][4], acc[2][4];
    #pragma unroll
    for (int s = 0; s < 2; s++) {
        afrag[s] = *(const bf16x8*)(Ag + (size_t)(bx * 2 + s) * 512 + lane * 8);
        #pragma unroll
        for (int r = 0; r < 4; r++) {
            si[s][r]  = scores[i0 + s * 16 + quad * 4 + r];
            acc[s][r] = 0.0f;
        }
    }

    const f32x4 zero = {0.0f, 0.0f, 0.0f, 0.0f};

    // B-frag prefetch pipeline, depth PF=2 (scores NOT prefetched: only the
    // ~2.7%-taken epilogue needs them)
    bf16x8 bpf[PF];
    #pragma unroll
    for (int q = 0; q < PF; q++) {
        const int tq = tb + ((q + phase) & (TPW - 1));
        bpf[q] = *(const bf16x8*)(Bg + (size_t)tq * 512 + lane * 8);
    }

    #pragma unroll 4
    for (int u = 0; u < TPW; u++) {
        bf16x8 bfrag = bpf[0];
        #pragma unroll
        for (int q = 0; q < PF - 1; q++) bpf[q] = bpf[q + 1];
        // issue next prefetch (wraps at end; harmless)
        const int tn = tb + ((u + PF + phase) & (TPW - 1));
        bpf[PF - 1] = *(const bf16x8*)(Bg + (size_t)tn * 512 + lane * 8);

        f32x4 d0 = __builtin_amdgcn_mfma_f32_16x16x32_bf16(afrag[0], bfrag, zero, 0, 0, 0);
        f32x4 d1 = __builtin_amdgcn_mfma_f32_16x16x32_bf16(afrag[1], bfrag, zero, 0, 0, 0);

        // v_max3 + v_max per half-tile
        float m0 = fmaxf(fmaxf(fmaxf(d0[0], d0[1]), d0[2]), d0[3]);
        float m1 = fmaxf(fmaxf(fmaxf(d1[0], d1[1]), d1[2]), d1[3]);
        if (__any(fmaxf(m0, m1) > SKIP_TH)) {
            const int tq = tb + ((u + phase) & (TPW - 1));
            float sj = scores[tq * 16 + half];     // rare load, L2-hit
            if (__any(m0 > SKIP_TH)) {
                #pragma unroll
                for (int r = 0; r < 4; r++) {
                    float e = __builtin_amdgcn_exp2f(d0[r]);
                    acc[0][r] += (sj > si[0][r]) ? e : 0.0f;
                }
            }
            if (__any(m1 > SKIP_TH)) {
                #pragma unroll
                for (int r = 0; r < 4; r++) {
                    float e = __builtin_amdgcn_exp2f(d1[r]);
                    acc[1][r] += (sj > si[1][r]) ? e : 0.0f;
                }
            }
        }
    }

    // reduce over 16 j-columns (half bits), then across 16 waves
    #pragma unroll
    for (int s = 0; s < 2; s++)
        #pragma unroll
        for (int r = 0; r < 4; r++) {
            float v = acc[s][r];
            v += __shfl_xor(v, 1);
            v += __shfl_xor(v, 2);
            v += __shfl_xor(v, 4);
            v += __shfl_xor(v, 8);
            if (half == 0) red[wid][s * 16 + quad * 4 + r] = v;
        }
    __syncthreads();
    if (t < IB) {
        float p = 0.0f;
        #pragma unroll
        for (int w = 0; w < NW; w++) p += red[w][t];
        out[i0 + t] = scores[i0 + t] * __builtin_amdgcn_exp2f(C2f * p);
    }
}

extern "C" void kernel_launch(void* const* d_in, const int* in_sizes, int n_in,
                              void* d_out, int out_size, void* d_ws, size_t ws_size,
                              hipStream_t stream) {
    const float* src    = (const float*)d_in[0];
    const float* tgt    = (const float*)d_in[1];
    const float* scores = (const float*)d_in[2];
    float* out = (float*)d_out;

    u16* Ag = (u16*)d_ws;                        // 512 KB, fragment-ordered
    u16* Bg = (u16*)((char*)d_ws + 524288);      // 512 KB, fragment-ordered

    prep_kernel<<<NPTS / 128, 128, 0, stream>>>(src, tgt, Ag, Bg);
    main_kernel<<<NBLK, BLOCK, 0, stream>>>(Ag, Bg, scores, out);
}